// Round 11
// baseline (50.697 us; speedup 1.0000x reference)
//
#include <hip/hip_runtime.h>

// Problem constants (StochPool: B=64, N_PER=1024, D=256, K=64, DEG=16)
#define NN 65536           // total nodes
#define DD 256             // feat dim
#define KK 64              // pools per graph
#define NPG 1024           // nodes per graph

// d_out layout (flat float32, outputs concatenated in return order)
#define OUT_OFF   0          // (4096, 256)
#define ADJ_OFF   1048576    // (64, 64, 64)
#define LINK_OFF  1310720    // scalar
#define ENT_OFF   1310721    // scalar
#define BATCH_OFF 1310722    // (4096,) as float
#define BPTR_OFF  1314818    // (65,) as float

// ws layout (bytes) — NOTHING here needs pre-zeroing (all plain stores)
#define WS_S1A    0          // int2 x 65536: {assign, s1 bits} (512 KB)
#define WS_C      524288     // float x 4096  (StS diagonal, by sort blocks)
#define WS_SQP    540672     // float x 256   (per-edge-block sum(w^2) partials)
#define WS_CRP    541696     // float x 256   (per-edge-block cross partials)
#define WS_ENTP   542720     // float x 1024  (per-pool-block entropy partials)
#define WS_SORTP  552960     // int2 x 65536: {node, s1 bits} sorted by cluster
#define WS_GOFF   1077248    // int32 x 64*65 (per-graph bin offsets)
#define WS_ADJP   1093888    // float x 256*4096 (per-edge-block adj partials, 4 MB)
#define WS_NEED   (WS_ADJP + 256 * 4096 * 4)

typedef __bf16 bf16x8 __attribute__((ext_vector_type(8)));
typedef unsigned short u16x8 __attribute__((ext_vector_type(8)));
typedef float f32x4 __attribute__((ext_vector_type(4)));

// f32 -> bf16 with round-to-nearest-even
static __device__ __forceinline__ unsigned short f2bf(float f) {
  unsigned int u = __float_as_uint(f);
  return (unsigned short)((u + 0x7fffu + ((u >> 16) & 1u)) >> 16);
}

// ---------------------------------------------------------------------------
// Kernel 1: logits GEMM via bf16 MFMA + in-register argmax/softmax.
// 1024 blocks x 256 threads (4 waves); block owns 64 consecutive nodes,
// wave wv owns nodes [nb0+16*wv, +16). Per wave: 4 N-tiles of
// mfma_f32_16x16x32_bf16 x 8 K-steps (K=256).
// Writes packed {assign, s1} int2 per node; entropy partial per block.
// ---------------------------------------------------------------------------
__global__ __launch_bounds__(256, 4) void pool_assign_kernel(
    const float* __restrict__ x, const float* __restrict__ Wm,
    const float* __restrict__ bvec, const float* __restrict__ gum,
    int2* __restrict__ s1a, float* __restrict__ entp)
{
  __shared__ unsigned short lds_wt[64 * 264];   // Wt[k][d] bf16, 33 KB
  __shared__ float esum[4];
  const int t    = threadIdx.x;
  const int lane = t & 63;
  const int wv   = t >> 6;
  const int q    = lane >> 4;     // k-quarter within frag
  const int c    = lane & 15;
  const int nb0  = blockIdx.x << 6;

  // stage Wt: lds_wt[k][d] = bf16(W[d][k]); coalesced global reads
  #pragma unroll 8
  for (int i = 0; i < 64; ++i) {
    int idx = (i << 8) + t;       // = d*64 + k
    lds_wt[(idx & 63) * 264 + (idx >> 6)] = f2bf(Wm[idx]);
  }

  // A-frags from global, converted to bf16, resident across N-tiles
  const int arow = nb0 + (wv << 4) + c;
  const float* xrow = x + (size_t)arow * DD + (q << 3);
  u16x8 afr[8];
  #pragma unroll
  for (int kb = 0; kb < 8; ++kb) {
    float4 u0 = *(const float4*)(xrow + kb * 32);
    float4 u1 = *(const float4*)(xrow + kb * 32 + 4);
    u16x8 af;
    af[0] = f2bf(u0.x); af[1] = f2bf(u0.y); af[2] = f2bf(u0.z); af[3] = f2bf(u0.w);
    af[4] = f2bf(u1.x); af[5] = f2bf(u1.y); af[6] = f2bf(u1.z); af[7] = f2bf(u1.w);
    afr[kb] = af;
  }
  __syncthreads();

  f32x4 acc[4];
  #pragma unroll
  for (int n = 0; n < 4; ++n) acc[n] = (f32x4){0.f, 0.f, 0.f, 0.f};
  #pragma unroll
  for (int n = 0; n < 4; ++n) {
    #pragma unroll
    for (int kb = 0; kb < 8; ++kb) {
      u16x8 bu = *(const u16x8*)(&lds_wt[(n * 16 + c) * 264 + kb * 32 + (q << 3)]);
      acc[n] = __builtin_amdgcn_mfma_f32_16x16x32_bf16(
          __builtin_bit_cast(bf16x8, afr[kb]),
          __builtin_bit_cast(bf16x8, bu), acc[n], 0, 0, 0);
    }
  }

  // epilogue: z = logits + b + gumbel; per-row argmax/softmax
  float bb[4];
  #pragma unroll
  for (int n = 0; n < 4; ++n) bb[n] = bvec[n * 16 + c];
  const int nodeq = nb0 + (wv << 4) + (q << 2);   // rows q*4..q*4+3
  float ent = 0.f;
  #pragma unroll
  for (int reg = 0; reg < 4; ++reg) {
    float zz[4];
    #pragma unroll
    for (int n = 0; n < 4; ++n)
      zz[n] = acc[n][reg] + bb[n] + gum[(size_t)(nodeq + reg) * KK + n * 16 + c];
    float m = zz[0]; int a = c;
    #pragma unroll
    for (int n = 1; n < 4; ++n)
      if (zz[n] > m) { m = zz[n]; a = n * 16 + c; }   // strict >: first max
    #pragma unroll
    for (int mask = 1; mask <= 8; mask <<= 1) {
      float mo = __shfl_xor(m, mask, 64);
      int   ao = __shfl_xor(a, mask, 64);
      if (mo > m || (mo == m && ao < a)) { m = mo; a = ao; }  // ties -> lower k
    }
    float ls = 0.f;
    #pragma unroll
    for (int n = 0; n < 4; ++n) ls += expf(zz[n] - m);
    #pragma unroll
    for (int mask = 1; mask <= 8; mask <<= 1) ls += __shfl_xor(ls, mask, 64);
    if (c == 0) {
      int node = nodeq + reg;
      float p  = 1.0f / ls;                 // softmax value at argmax
      float s1 = (1.0f - p) + p;            // straight-through value (≈1)
      s1a[node] = make_int2(a, __float_as_int(s1));
      ent += -s1 * logf(s1 + 1e-15f);       // non-argmax terms are exactly 0
    }
  }
  #pragma unroll
  for (int off = 32; off; off >>= 1) ent += __shfl_down(ent, off, 64);
  if (lane == 0) esum[wv] = ent;
  __syncthreads();
  if (t == 0) entp[blockIdx.x] = esum[0] + esum[1] + esum[2] + esum[3];
}

// ---------------------------------------------------------------------------
// Kernel 2 (fused): blocks [0,256) = edge adjacency (latency-bound scatter,
// resident from t=0); blocks [256,320) = per-graph counting sort + StS diag
// (tiny, hides under the edges). Both depend only on s1a.
// ---------------------------------------------------------------------------
__global__ __launch_bounds__(256, 8) void sortedge_kernel(
    const int* __restrict__ src, const int* __restrict__ dst,
    const float* __restrict__ ew, const int2* __restrict__ s1a,
    float* __restrict__ adjp, float* __restrict__ sqP, float* __restrict__ crP,
    int2* __restrict__ sortedp, int* __restrict__ goff, float* __restrict__ c_out)
{
  __shared__ float adj[4096];            // 16 KB (edge path)
  __shared__ float redsq[4], redcr[4];
  __shared__ int hist[64];
  __shared__ int offs[65];
  __shared__ int cursor[64];
  __shared__ float cbin[64];
  const int t = threadIdx.x;
  if (blockIdx.x < 256) {
    // ---- edges: block blk owns edges [blk*4096, +4096) ----
    const int blk = blockIdx.x;
    #pragma unroll
    for (int i = 0; i < 16; ++i) adj[i * 256 + t] = 0.f;
    __syncthreads();
    const int e0 = blk << 12;
    float sq = 0.f, cr = 0.f;
    #pragma unroll 4
    for (int i = 0; i < 16; ++i) {
      int e = e0 + (i << 8) + t;
      int u = src[e], v = dst[e];
      float w = ew[e];
      int2 pu = s1a[u];
      int2 pv = s1a[v];
      float contrib = w * __int_as_float(pu.y) * __int_as_float(pv.y);
      atomicAdd(&adj[pu.x * 64 + pv.x], contrib);   // ds_add_f32
      sq += w * w;
      if (pu.x == pv.x) cr += contrib;
    }
    #pragma unroll
    for (int off = 32; off; off >>= 1) {
      sq += __shfl_down(sq, off, 64);
      cr += __shfl_down(cr, off, 64);
    }
    if ((t & 63) == 0) { redsq[t >> 6] = sq; redcr[t >> 6] = cr; }
    __syncthreads();
    if (t == 0) {
      sqP[blk] = redsq[0] + redsq[1] + redsq[2] + redsq[3];
      crP[blk] = redcr[0] + redcr[1] + redcr[2] + redcr[3];
    }
    float* pp = adjp + (size_t)blk * 4096;
    #pragma unroll
    for (int i = 0; i < 16; ++i) pp[i * 256 + t] = adj[i * 256 + t];
  } else {
    // ---- sort: graph g = blockIdx.x - 256; 256 threads x 4 nodes ----
    const int g = blockIdx.x - 256;
    const int n0 = g << 10;
    if (t < 64) { hist[t] = 0; cbin[t] = 0.f; }
    __syncthreads();
    int4 p01 = ((const int4*)(s1a + n0))[t * 2];
    int4 p23 = ((const int4*)(s1a + n0))[t * 2 + 1];
    atomicAdd(&hist[p01.x], 1);
    atomicAdd(&hist[p01.z], 1);
    atomicAdd(&hist[p23.x], 1);
    atomicAdd(&hist[p23.z], 1);
    float s0 = __int_as_float(p01.y), s1v = __int_as_float(p01.w);
    float s2 = __int_as_float(p23.y), s3v = __int_as_float(p23.w);
    atomicAdd(&cbin[p01.x], s0 * s0);
    atomicAdd(&cbin[p01.z], s1v * s1v);
    atomicAdd(&cbin[p23.x], s2 * s2);
    atomicAdd(&cbin[p23.z], s3v * s3v);
    __syncthreads();
    if (t == 0) {
      int s = 0;
      #pragma unroll
      for (int k = 0; k < 64; ++k) { offs[k] = s; s += hist[k]; }
      offs[64] = s;   // = 1024
    }
    __syncthreads();
    if (t < 64) cursor[t] = offs[t];
    if (t < 65) goff[g * 65 + t] = offs[t];
    if (t < 64) c_out[(g << 6) + t] = cbin[t];
    __syncthreads();
    int p;
    p = atomicAdd(&cursor[p01.x], 1); sortedp[n0 + p] = make_int2(n0 + t * 4 + 0, p01.y);
    p = atomicAdd(&cursor[p01.z], 1); sortedp[n0 + p] = make_int2(n0 + t * 4 + 1, p01.w);
    p = atomicAdd(&cursor[p23.x], 1); sortedp[n0 + p] = make_int2(n0 + t * 4 + 2, p23.y);
    p = atomicAdd(&cursor[p23.z], 1); sortedp[n0 + p] = make_int2(n0 + t * 4 + 3, p23.w);
  }
}

// ---------------------------------------------------------------------------
// Kernel 3 (fused): blocks [0,4096) = pooled-feature gather; blocks
// [4096,4352) = adjacency combine (4 partials/graph); block 4352 = finalize
// (link/entropy scalars + batch/batch_ptr tails). All inputs come from
// dispatches 1-2, so co-dispatch is race-free.
// ---------------------------------------------------------------------------
__global__ __launch_bounds__(256, 8) void gatherfin_kernel(
    const float* __restrict__ x, const int2* __restrict__ sortedp,
    const int* __restrict__ goff, const float* __restrict__ adjp,
    const float* __restrict__ c, const float* __restrict__ sqP,
    const float* __restrict__ crP, const float* __restrict__ entp,
    float* __restrict__ out)
{
  __shared__ float ered[4];
  const int t = threadIdx.x;
  if (blockIdx.x < 4096) {
    // ---- gather: (graph g, cluster k), thread t = output dim ----
    const int g = blockIdx.x >> 6;
    const int k = blockIdx.x & 63;
    const int o0 = goff[g * 65 + k];
    const int o1 = goff[g * 65 + k + 1];
    const int2* sp = sortedp + (g << 10);
    float sum = 0.f;
    int i = o0;
    for (; i + 4 <= o1; i += 4) {
      int2 e0 = sp[i], e1 = sp[i + 1], e2 = sp[i + 2], e3 = sp[i + 3];
      float x0 = x[(size_t)e0.x * DD + t];
      float x1 = x[(size_t)e1.x * DD + t];
      float x2 = x[(size_t)e2.x * DD + t];
      float x3 = x[(size_t)e3.x * DD + t];
      sum += __int_as_float(e0.y) * x0 + __int_as_float(e1.y) * x1
           + __int_as_float(e2.y) * x2 + __int_as_float(e3.y) * x3;
    }
    for (; i < o1; ++i) {
      int2 e = sp[i];
      sum += __int_as_float(e.y) * x[(size_t)e.x * DD + t];
    }
    out[OUT_OFF + ((size_t)((g << 6) + k)) * DD + t] = sum;
  } else if (blockIdx.x < 4352) {
    // ---- adj combine: 256 blocks x 4 cells/thread = 262144 cells ----
    const int blkc = blockIdx.x - 4096;
    #pragma unroll
    for (int i = 0; i < 4; ++i) {
      int idx = blkc * 1024 + (i << 8) + t;
      int g = idx >> 12;
      int cell = idx & 4095;
      const float* p = adjp + ((size_t)(g * 4)) * 4096 + cell;
      out[ADJ_OFF + idx] = p[0] + p[4096] + p[8192] + p[12288];
    }
  } else {
    // ---- finalize (one block, 256 threads) ----
    float ent = entp[t] + entp[t + 256] + entp[t + 512] + entp[t + 768];
    #pragma unroll
    for (int off = 32; off; off >>= 1) ent += __shfl_down(ent, off, 64);
    if ((t & 63) == 0) ered[t >> 6] = ent;
    float link = 0.f;
    if (t < 64) {
      const float* cg = c + t * 64;
      float ssq = 0.f;
      #pragma unroll
      for (int k = 0; k < 64; ++k) ssq += cg[k] * cg[k];
      float sq = sqP[t * 4] + sqP[t * 4 + 1] + sqP[t * 4 + 2] + sqP[t * 4 + 3];
      float cr = crP[t * 4] + crP[t * 4 + 1] + crP[t * 4 + 2] + crP[t * 4 + 3];
      float val = sq - 2.0f * cr + ssq;
      link = sqrtf(fmaxf(val, 0.f)) / 16384.0f;   // e_per = 16384
      #pragma unroll
      for (int off = 32; off; off >>= 1) link += __shfl_down(link, off, 64);
    }
    __syncthreads();
    if (t == 0) {
      out[LINK_OFF] = link / 64.0f;
      out[ENT_OFF]  = (ered[0] + ered[1] + ered[2] + ered[3]) / (float)NN;
    }
    for (int r = t; r < 4096; r += 256) out[BATCH_OFF + r] = (float)(r >> 6);
    for (int i = t; i < 65; i += 256)   out[BPTR_OFF + i]  = (float)(i << 6);
  }
}

// ---------------------------------------------------------------------------
// Fallback path (small ws): global-atomic adjacency, out_adj pre-zeroed.
// ---------------------------------------------------------------------------
__global__ __launch_bounds__(256) void edge_atomic_kernel(
    const int* __restrict__ src, const int* __restrict__ dst,
    const float* __restrict__ ew, const int2* __restrict__ s1a,
    float* __restrict__ out_adj, float* __restrict__ sqP, float* __restrict__ crP)
{
  __shared__ float adj[4096];
  __shared__ float redsq[4], redcr[4];
  const int t = threadIdx.x;
  const int blk = blockIdx.x;
  const int g = blk >> 2;
  #pragma unroll
  for (int i = 0; i < 16; ++i) adj[i * 256 + t] = 0.f;
  __syncthreads();
  const int e0 = blk << 12;
  float sq = 0.f, cr = 0.f;
  #pragma unroll 4
  for (int i = 0; i < 16; ++i) {
    int e = e0 + (i << 8) + t;
    int u = src[e], v = dst[e];
    float w = ew[e];
    int2 pu = s1a[u];
    int2 pv = s1a[v];
    float contrib = w * __int_as_float(pu.y) * __int_as_float(pv.y);
    atomicAdd(&adj[pu.x * 64 + pv.x], contrib);
    sq += w * w;
    if (pu.x == pv.x) cr += contrib;
  }
  #pragma unroll
  for (int off = 32; off; off >>= 1) {
    sq += __shfl_down(sq, off, 64);
    cr += __shfl_down(cr, off, 64);
  }
  if ((t & 63) == 0) { redsq[t >> 6] = sq; redcr[t >> 6] = cr; }
  __syncthreads();
  if (t == 0) {
    sqP[blk] = redsq[0] + redsq[1] + redsq[2] + redsq[3];
    crP[blk] = redcr[0] + redcr[1] + redcr[2] + redcr[3];
  }
  float* adjg = out_adj + (size_t)g * 4096;
  #pragma unroll
  for (int i = 0; i < 16; ++i) atomicAdd(&adjg[i * 256 + t], adj[i * 256 + t]);
}

__global__ __launch_bounds__(256) void sort_only_kernel(
    const int2* __restrict__ s1a, int2* __restrict__ sortedp,
    int* __restrict__ goff, float* __restrict__ c_out)
{
  __shared__ int hist[64];
  __shared__ int offs[65];
  __shared__ int cursor[64];
  __shared__ float cbin[64];
  const int t = threadIdx.x;
  const int g = blockIdx.x;
  const int n0 = g << 10;
  if (t < 64) { hist[t] = 0; cbin[t] = 0.f; }
  __syncthreads();
  int4 p01 = ((const int4*)(s1a + n0))[t * 2];
  int4 p23 = ((const int4*)(s1a + n0))[t * 2 + 1];
  atomicAdd(&hist[p01.x], 1);
  atomicAdd(&hist[p01.z], 1);
  atomicAdd(&hist[p23.x], 1);
  atomicAdd(&hist[p23.z], 1);
  float s0 = __int_as_float(p01.y), s1v = __int_as_float(p01.w);
  float s2 = __int_as_float(p23.y), s3v = __int_as_float(p23.w);
  atomicAdd(&cbin[p01.x], s0 * s0);
  atomicAdd(&cbin[p01.z], s1v * s1v);
  atomicAdd(&cbin[p23.x], s2 * s2);
  atomicAdd(&cbin[p23.z], s3v * s3v);
  __syncthreads();
  if (t == 0) {
    int s = 0;
    #pragma unroll
    for (int k = 0; k < 64; ++k) { offs[k] = s; s += hist[k]; }
    offs[64] = s;
  }
  __syncthreads();
  if (t < 64) cursor[t] = offs[t];
  if (t < 65) goff[g * 65 + t] = offs[t];
  if (t < 64) c_out[(g << 6) + t] = cbin[t];
  __syncthreads();
  int p;
  p = atomicAdd(&cursor[p01.x], 1); sortedp[n0 + p] = make_int2(n0 + t * 4 + 0, p01.y);
  p = atomicAdd(&cursor[p01.z], 1); sortedp[n0 + p] = make_int2(n0 + t * 4 + 1, p01.w);
  p = atomicAdd(&cursor[p23.x], 1); sortedp[n0 + p] = make_int2(n0 + t * 4 + 2, p23.y);
  p = atomicAdd(&cursor[p23.z], 1); sortedp[n0 + p] = make_int2(n0 + t * 4 + 3, p23.w);
}

__global__ __launch_bounds__(256, 8) void gather_kernel(
    const float* __restrict__ x, const int2* __restrict__ sortedp,
    const int* __restrict__ goff, float* __restrict__ out_feat)
{
  const int t = threadIdx.x;
  const int g = blockIdx.x >> 6;
  const int k = blockIdx.x & 63;
  const int o0 = goff[g * 65 + k];
  const int o1 = goff[g * 65 + k + 1];
  const int2* sp = sortedp + (g << 10);
  float sum = 0.f;
  for (int i = o0; i < o1; ++i) {
    int2 e = sp[i];
    sum += __int_as_float(e.y) * x[(size_t)e.x * DD + t];
  }
  out_feat[((size_t)((g << 6) + k)) * DD + t] = sum;
}

__global__ __launch_bounds__(256) void finalize_only_kernel(
    const float* __restrict__ c, const float* __restrict__ sqP,
    const float* __restrict__ crP, const float* __restrict__ entp,
    float* __restrict__ out)
{
  __shared__ float ered[4];
  const int t = threadIdx.x;
  float ent = entp[t] + entp[t + 256] + entp[t + 512] + entp[t + 768];
  #pragma unroll
  for (int off = 32; off; off >>= 1) ent += __shfl_down(ent, off, 64);
  if ((t & 63) == 0) ered[t >> 6] = ent;
  float link = 0.f;
  if (t < 64) {
    const float* cg = c + t * 64;
    float ssq = 0.f;
    #pragma unroll
    for (int k = 0; k < 64; ++k) ssq += cg[k] * cg[k];
    float sq = sqP[t * 4] + sqP[t * 4 + 1] + sqP[t * 4 + 2] + sqP[t * 4 + 3];
    float cr = crP[t * 4] + crP[t * 4 + 1] + crP[t * 4 + 2] + crP[t * 4 + 3];
    float val = sq - 2.0f * cr + ssq;
    link = sqrtf(fmaxf(val, 0.f)) / 16384.0f;
    #pragma unroll
    for (int off = 32; off; off >>= 1) link += __shfl_down(link, off, 64);
  }
  __syncthreads();
  if (t == 0) {
    out[LINK_OFF] = link / 64.0f;
    out[ENT_OFF]  = (ered[0] + ered[1] + ered[2] + ered[3]) / (float)NN;
  }
  for (int r = t; r < 4096; r += 256) out[BATCH_OFF + r] = (float)(r >> 6);
  for (int i = t; i < 65; i += 256)   out[BPTR_OFF + i]  = (float)(i << 6);
}

extern "C" void kernel_launch(void* const* d_in, const int* in_sizes, int n_in,
                              void* d_out, int out_size, void* d_ws, size_t ws_size,
                              hipStream_t stream) {
  const float* x    = (const float*)d_in[0];
  const float* ew   = (const float*)d_in[1];
  const float* Wm   = (const float*)d_in[2];
  const float* bvec = (const float*)d_in[3];
  const float* gum  = (const float*)d_in[4];
  const int*   eidx = (const int*)d_in[5];
  float* out = (float*)d_out;
  char*  ws  = (char*)d_ws;

  int2*  s1a     = (int2*)(ws + WS_S1A);
  float* c       = (float*)(ws + WS_C);
  float* sqP     = (float*)(ws + WS_SQP);
  float* crP     = (float*)(ws + WS_CRP);
  float* entp    = (float*)(ws + WS_ENTP);
  int2*  sortedp = (int2*)(ws + WS_SORTP);
  int*   goff    = (int*)(ws + WS_GOFF);
  float* adjp    = (float*)(ws + WS_ADJP);

  const int E = in_sizes[1];   // 1048576

  pool_assign_kernel<<<1024, 256, 0, stream>>>(x, Wm, bvec, gum, s1a, entp);
  if (ws_size >= (size_t)WS_NEED) {
    sortedge_kernel<<<320, 256, 0, stream>>>(eidx, eidx + E, ew, s1a,
                                             adjp, sqP, crP, sortedp, goff, c);
    gatherfin_kernel<<<4353, 256, 0, stream>>>(x, sortedp, goff, adjp,
                                               c, sqP, crP, entp, out);
  } else {
    hipMemsetAsync(out + ADJ_OFF, 0, (size_t)64 * 4096 * 4, stream);
    sort_only_kernel<<<64, 256, 0, stream>>>(s1a, sortedp, goff, c);
    gather_kernel<<<4096, 256, 0, stream>>>(x, sortedp, goff, out + OUT_OFF);
    edge_atomic_kernel<<<256, 256, 0, stream>>>(eidx, eidx + E, ew, s1a,
                                                out + ADJ_OFF, sqP, crP);
    finalize_only_kernel<<<1, 256, 0, stream>>>(c, sqP, crP, entp, out);
  }
}

// Round 12
// 48.964 us; speedup vs baseline: 1.0354x; 1.0354x over previous
//
#include <hip/hip_runtime.h>

// Problem constants (StochPool: B=64, N_PER=1024, D=256, K=64, DEG=16)
#define NN 65536           // total nodes
#define DD 256             // feat dim
#define KK 64              // pools per graph
#define NPG 1024           // nodes per graph

// d_out layout (flat float32, outputs concatenated in return order)
#define OUT_OFF   0          // (4096, 256)
#define ADJ_OFF   1048576    // (64, 64, 64)
#define LINK_OFF  1310720    // scalar
#define ENT_OFF   1310721    // scalar
#define BATCH_OFF 1310722    // (4096,) as float
#define BPTR_OFF  1314818    // (65,) as float

// ws layout (bytes) — NOTHING here needs pre-zeroing (all plain stores)
#define WS_S1A    0          // int2 x 65536: {assign, s1 bits} (512 KB)
#define WS_C      524288     // float x 4096  (StS diagonal, by sort_kernel)
#define WS_SQP    540672     // float x 256   (per-edge-block sum(w^2) partials)
#define WS_CRP    541696     // float x 256   (per-edge-block cross partials)
#define WS_ENTP   542720     // float x 1024  (per-pool-block entropy partials)
#define WS_SORTP  552960     // int2 x 65536: {node, s1 bits} sorted by cluster
#define WS_GOFF   1077248    // int32 x 64*65 (per-graph bin offsets)
#define WS_ADJP   1093888    // float x 256*4096 (per-edge-block adj partials, 4 MB)
#define WS_NEED   (WS_ADJP + 256 * 4096 * 4)

typedef __bf16 bf16x8 __attribute__((ext_vector_type(8)));
typedef unsigned short u16x8 __attribute__((ext_vector_type(8)));
typedef float f32x4 __attribute__((ext_vector_type(4)));

// f32 -> bf16 with round-to-nearest-even
static __device__ __forceinline__ unsigned short f2bf(float f) {
  unsigned int u = __float_as_uint(f);
  return (unsigned short)((u + 0x7fffu + ((u >> 16) & 1u)) >> 16);
}

// ---------------------------------------------------------------------------
// Kernel 1: logits GEMM via bf16 MFMA + in-register argmax/softmax.
// 1024 blocks x 256 threads (4 waves); block owns 64 consecutive nodes,
// wave wv owns nodes [nb0+16*wv, +16). Per wave: 4 N-tiles of
// mfma_f32_16x16x32_bf16 x 8 K-steps (K=256).
// Writes packed {assign, s1} int2 per node; entropy partial per block.
// ---------------------------------------------------------------------------
__global__ __launch_bounds__(256, 4) void pool_assign_kernel(
    const float* __restrict__ x, const float* __restrict__ Wm,
    const float* __restrict__ bvec, const float* __restrict__ gum,
    int2* __restrict__ s1a, float* __restrict__ entp)
{
  __shared__ unsigned short lds_wt[64 * 264];   // Wt[k][d] bf16, 33 KB
  __shared__ float esum[4];
  const int t    = threadIdx.x;
  const int lane = t & 63;
  const int wv   = t >> 6;
  const int q    = lane >> 4;     // k-quarter within frag
  const int c    = lane & 15;
  const int nb0  = blockIdx.x << 6;

  // stage Wt: lds_wt[k][d] = bf16(W[d][k]); coalesced global reads
  #pragma unroll 8
  for (int i = 0; i < 64; ++i) {
    int idx = (i << 8) + t;       // = d*64 + k
    lds_wt[(idx & 63) * 264 + (idx >> 6)] = f2bf(Wm[idx]);
  }

  // A-frags from global, converted to bf16, resident across N-tiles
  const int arow = nb0 + (wv << 4) + c;
  const float* xrow = x + (size_t)arow * DD + (q << 3);
  u16x8 afr[8];
  #pragma unroll
  for (int kb = 0; kb < 8; ++kb) {
    float4 u0 = *(const float4*)(xrow + kb * 32);
    float4 u1 = *(const float4*)(xrow + kb * 32 + 4);
    u16x8 af;
    af[0] = f2bf(u0.x); af[1] = f2bf(u0.y); af[2] = f2bf(u0.z); af[3] = f2bf(u0.w);
    af[4] = f2bf(u1.x); af[5] = f2bf(u1.y); af[6] = f2bf(u1.z); af[7] = f2bf(u1.w);
    afr[kb] = af;
  }
  __syncthreads();

  f32x4 acc[4];
  #pragma unroll
  for (int n = 0; n < 4; ++n) acc[n] = (f32x4){0.f, 0.f, 0.f, 0.f};
  #pragma unroll
  for (int n = 0; n < 4; ++n) {
    #pragma unroll
    for (int kb = 0; kb < 8; ++kb) {
      u16x8 bu = *(const u16x8*)(&lds_wt[(n * 16 + c) * 264 + kb * 32 + (q << 3)]);
      acc[n] = __builtin_amdgcn_mfma_f32_16x16x32_bf16(
          __builtin_bit_cast(bf16x8, afr[kb]),
          __builtin_bit_cast(bf16x8, bu), acc[n], 0, 0, 0);
    }
  }

  // epilogue: z = logits + b + gumbel; per-row argmax/softmax
  float bb[4];
  #pragma unroll
  for (int n = 0; n < 4; ++n) bb[n] = bvec[n * 16 + c];
  const int nodeq = nb0 + (wv << 4) + (q << 2);   // rows q*4..q*4+3
  float ent = 0.f;
  #pragma unroll
  for (int reg = 0; reg < 4; ++reg) {
    float zz[4];
    #pragma unroll
    for (int n = 0; n < 4; ++n)
      zz[n] = acc[n][reg] + bb[n] + gum[(size_t)(nodeq + reg) * KK + n * 16 + c];
    float m = zz[0]; int a = c;
    #pragma unroll
    for (int n = 1; n < 4; ++n)
      if (zz[n] > m) { m = zz[n]; a = n * 16 + c; }   // strict >: first max
    #pragma unroll
    for (int mask = 1; mask <= 8; mask <<= 1) {
      float mo = __shfl_xor(m, mask, 64);
      int   ao = __shfl_xor(a, mask, 64);
      if (mo > m || (mo == m && ao < a)) { m = mo; a = ao; }  // ties -> lower k
    }
    float ls = 0.f;
    #pragma unroll
    for (int n = 0; n < 4; ++n) ls += expf(zz[n] - m);
    #pragma unroll
    for (int mask = 1; mask <= 8; mask <<= 1) ls += __shfl_xor(ls, mask, 64);
    if (c == 0) {
      int node = nodeq + reg;
      float p  = 1.0f / ls;                 // softmax value at argmax
      float s1 = (1.0f - p) + p;            // straight-through value (≈1)
      s1a[node] = make_int2(a, __float_as_int(s1));
      ent += -s1 * logf(s1 + 1e-15f);       // non-argmax terms are exactly 0
    }
  }
  #pragma unroll
  for (int off = 32; off; off >>= 1) ent += __shfl_down(ent, off, 64);
  if (lane == 0) esum[wv] = ent;
  __syncthreads();
  if (t == 0) entp[blockIdx.x] = esum[0] + esum[1] + esum[2] + esum[3];
}

// ---------------------------------------------------------------------------
// Kernel 2: per-graph counting sort (packed entries) + StS diagonal.
// 64 blocks (one per graph) x 256 threads x 4 nodes.
// c accumulated via LDS atomics in the main pass (no serial per-bin tail).
// ---------------------------------------------------------------------------
__global__ __launch_bounds__(256) void sort_kernel(
    const int2* __restrict__ s1a, int2* __restrict__ sortedp,
    int* __restrict__ goff, float* __restrict__ c_out)
{
  __shared__ int hist[64];
  __shared__ int offs[65];
  __shared__ int cursor[64];
  __shared__ float cbin[64];
  const int t = threadIdx.x;
  const int g = blockIdx.x;
  const int n0 = g << 10;
  if (t < 64) { hist[t] = 0; cbin[t] = 0.f; }
  __syncthreads();
  // nodes t*4 .. t*4+3 packed pairs: {a0,s0,a1,s1},{a2,s2,a3,s3}
  int4 p01 = ((const int4*)(s1a + n0))[t * 2];
  int4 p23 = ((const int4*)(s1a + n0))[t * 2 + 1];
  atomicAdd(&hist[p01.x], 1);
  atomicAdd(&hist[p01.z], 1);
  atomicAdd(&hist[p23.x], 1);
  atomicAdd(&hist[p23.z], 1);
  float s0 = __int_as_float(p01.y), s1v = __int_as_float(p01.w);
  float s2 = __int_as_float(p23.y), s3v = __int_as_float(p23.w);
  atomicAdd(&cbin[p01.x], s0 * s0);
  atomicAdd(&cbin[p01.z], s1v * s1v);
  atomicAdd(&cbin[p23.x], s2 * s2);
  atomicAdd(&cbin[p23.z], s3v * s3v);
  __syncthreads();
  if (t == 0) {
    int s = 0;
    #pragma unroll
    for (int k = 0; k < 64; ++k) { offs[k] = s; s += hist[k]; }
    offs[64] = s;   // = 1024
  }
  __syncthreads();
  if (t < 64) cursor[t] = offs[t];
  if (t < 65) goff[g * 65 + t] = offs[t];
  if (t < 64) c_out[(g << 6) + t] = cbin[t];
  __syncthreads();
  int p;
  p = atomicAdd(&cursor[p01.x], 1); sortedp[n0 + p] = make_int2(n0 + t * 4 + 0, p01.y);
  p = atomicAdd(&cursor[p01.z], 1); sortedp[n0 + p] = make_int2(n0 + t * 4 + 1, p01.w);
  p = atomicAdd(&cursor[p23.x], 1); sortedp[n0 + p] = make_int2(n0 + t * 4 + 2, p23.y);
  p = atomicAdd(&cursor[p23.z], 1); sortedp[n0 + p] = make_int2(n0 + t * 4 + 3, p23.w);
}

// ---------------------------------------------------------------------------
// Kernel 3 (fused): blocks [0,256) = edge adjacency (issued FIRST so the
// latency-bound scatter work is resident from t=0); blocks [256,4352) =
// pooled-feature gather (HBM streaming, overlaps the edges). The overlap of
// these two regimes in ONE dispatch is the measured win (round 10 vs 11).
// ---------------------------------------------------------------------------
__global__ __launch_bounds__(256, 8) void fuse_ge_kernel(
    const float* __restrict__ x, const int2* __restrict__ sortedp,
    const int* __restrict__ goff, const int* __restrict__ src,
    const int* __restrict__ dst, const float* __restrict__ ew,
    const int2* __restrict__ s1a, float* __restrict__ out_feat,
    float* __restrict__ adjp, float* __restrict__ sqP, float* __restrict__ crP)
{
  __shared__ float adj[4096];
  __shared__ float redsq[4], redcr[4];
  const int t = threadIdx.x;
  if (blockIdx.x < 256) {
    // ---- edges: block blk owns edges [blk*4096, +4096) ----
    const int blk = blockIdx.x;
    #pragma unroll
    for (int i = 0; i < 16; ++i) adj[i * 256 + t] = 0.f;
    __syncthreads();
    const int e0 = blk << 12;
    float sq = 0.f, cr = 0.f;
    #pragma unroll 4
    for (int i = 0; i < 16; ++i) {
      int e = e0 + (i << 8) + t;
      int u = src[e], v = dst[e];
      float w = ew[e];
      int2 pu = s1a[u];
      int2 pv = s1a[v];
      float contrib = w * __int_as_float(pu.y) * __int_as_float(pv.y);
      atomicAdd(&adj[pu.x * 64 + pv.x], contrib);   // ds_add_f32
      sq += w * w;
      if (pu.x == pv.x) cr += contrib;
    }
    #pragma unroll
    for (int off = 32; off; off >>= 1) {
      sq += __shfl_down(sq, off, 64);
      cr += __shfl_down(cr, off, 64);
    }
    if ((t & 63) == 0) { redsq[t >> 6] = sq; redcr[t >> 6] = cr; }
    __syncthreads();
    if (t == 0) {
      sqP[blk] = redsq[0] + redsq[1] + redsq[2] + redsq[3];
      crP[blk] = redcr[0] + redcr[1] + redcr[2] + redcr[3];
    }
    float* pp = adjp + (size_t)blk * 4096;
    #pragma unroll
    for (int i = 0; i < 16; ++i) pp[i * 256 + t] = adj[i * 256 + t];
  } else {
    // ---- gather: (graph g, cluster k), thread t = output dim ----
    const int bk = blockIdx.x - 256;
    const int g = bk >> 6;
    const int k = bk & 63;
    const int o0 = goff[g * 65 + k];
    const int o1 = goff[g * 65 + k + 1];
    const int2* sp = sortedp + (g << 10);
    float sum = 0.f;
    int i = o0;
    for (; i + 4 <= o1; i += 4) {
      int2 e0 = sp[i], e1 = sp[i + 1], e2 = sp[i + 2], e3 = sp[i + 3];
      float x0 = x[(size_t)e0.x * DD + t];
      float x1 = x[(size_t)e1.x * DD + t];
      float x2 = x[(size_t)e2.x * DD + t];
      float x3 = x[(size_t)e3.x * DD + t];
      sum += __int_as_float(e0.y) * x0 + __int_as_float(e1.y) * x1
           + __int_as_float(e2.y) * x2 + __int_as_float(e3.y) * x3;
    }
    for (; i < o1; ++i) {
      int2 e = sp[i];
      sum += __int_as_float(e.y) * x[(size_t)e.x * DD + t];
    }
    out_feat[((size_t)((g << 6) + k)) * DD + t] = sum;
  }
}

// ---------------------------------------------------------------------------
// Kernel 4 (fused): blocks 0..255 combine 4 adjacency partials per graph;
// block 256 computes link/entropy scalars + batch/batch_ptr tails.
// ---------------------------------------------------------------------------
__global__ __launch_bounds__(1024) void combine_fin_kernel(
    const float* __restrict__ adjp, const float* __restrict__ c,
    const float* __restrict__ sqP, const float* __restrict__ crP,
    const float* __restrict__ entp, float* __restrict__ out)
{
  __shared__ float ered[16];
  const int t = threadIdx.x;
  if (blockIdx.x < 256) {
    int idx = blockIdx.x * 1024 + t;      // 262144 cells
    int g = idx >> 12;
    int cell = idx & 4095;
    const float* p = adjp + ((size_t)(g * 4)) * 4096 + cell;
    out[ADJ_OFF + idx] = p[0] + p[4096] + p[8192] + p[12288];
    return;
  }
  // finalize (block 256, 1024 threads)
  float ent = entp[t];                    // 1024 partials, one per thread
  #pragma unroll
  for (int off = 32; off; off >>= 1) ent += __shfl_down(ent, off, 64);
  if ((t & 63) == 0) ered[t >> 6] = ent;
  float link = 0.f;
  if (t < 64) {
    const float* cg = c + t * 64;
    float ssq = 0.f;
    #pragma unroll
    for (int k = 0; k < 64; ++k) ssq += cg[k] * cg[k];
    float sq = sqP[t * 4] + sqP[t * 4 + 1] + sqP[t * 4 + 2] + sqP[t * 4 + 3];
    float cr = crP[t * 4] + crP[t * 4 + 1] + crP[t * 4 + 2] + crP[t * 4 + 3];
    float val = sq - 2.0f * cr + ssq;
    link = sqrtf(fmaxf(val, 0.f)) / 16384.0f;   // e_per = 16384
    #pragma unroll
    for (int off = 32; off; off >>= 1) link += __shfl_down(link, off, 64);
  }
  __syncthreads();
  if (t == 0) {
    float es = 0.f;
    #pragma unroll
    for (int i = 0; i < 16; ++i) es += ered[i];
    out[LINK_OFF] = link / 64.0f;
    out[ENT_OFF]  = es / (float)NN;
  }
  for (int r = t; r < 4096; r += 1024) out[BATCH_OFF + r] = (float)(r >> 6);
  if (t < 65) out[BPTR_OFF + t] = (float)(t << 6);
}

// Fallback edge kernel (small ws): global atomics, out_adj pre-zeroed.
__global__ __launch_bounds__(256) void edge_atomic_kernel(
    const int* __restrict__ src, const int* __restrict__ dst,
    const float* __restrict__ ew, const int2* __restrict__ s1a,
    float* __restrict__ out_adj, float* __restrict__ sqP, float* __restrict__ crP)
{
  __shared__ float adj[4096];
  __shared__ float redsq[4], redcr[4];
  const int t = threadIdx.x;
  const int blk = blockIdx.x;
  const int g = blk >> 2;
  #pragma unroll
  for (int i = 0; i < 16; ++i) adj[i * 256 + t] = 0.f;
  __syncthreads();
  const int e0 = blk << 12;
  float sq = 0.f, cr = 0.f;
  #pragma unroll 4
  for (int i = 0; i < 16; ++i) {
    int e = e0 + (i << 8) + t;
    int u = src[e], v = dst[e];
    float w = ew[e];
    int2 pu = s1a[u];
    int2 pv = s1a[v];
    float contrib = w * __int_as_float(pu.y) * __int_as_float(pv.y);
    atomicAdd(&adj[pu.x * 64 + pv.x], contrib);
    sq += w * w;
    if (pu.x == pv.x) cr += contrib;
  }
  #pragma unroll
  for (int off = 32; off; off >>= 1) {
    sq += __shfl_down(sq, off, 64);
    cr += __shfl_down(cr, off, 64);
  }
  if ((t & 63) == 0) { redsq[t >> 6] = sq; redcr[t >> 6] = cr; }
  __syncthreads();
  if (t == 0) {
    sqP[blk] = redsq[0] + redsq[1] + redsq[2] + redsq[3];
    crP[blk] = redcr[0] + redcr[1] + redcr[2] + redcr[3];
  }
  float* adjg = out_adj + (size_t)g * 4096;
  #pragma unroll
  for (int i = 0; i < 16; ++i) atomicAdd(&adjg[i * 256 + t], adj[i * 256 + t]);
}

// Fallback gather-only (paired with edge_atomic path).
__global__ __launch_bounds__(256, 8) void gather_kernel(
    const float* __restrict__ x, const int2* __restrict__ sortedp,
    const int* __restrict__ goff, float* __restrict__ out_feat)
{
  const int t = threadIdx.x;
  const int g = blockIdx.x >> 6;
  const int k = blockIdx.x & 63;
  const int o0 = goff[g * 65 + k];
  const int o1 = goff[g * 65 + k + 1];
  const int2* sp = sortedp + (g << 10);
  float sum = 0.f;
  for (int i = o0; i < o1; ++i) {
    int2 e = sp[i];
    sum += __int_as_float(e.y) * x[(size_t)e.x * DD + t];
  }
  out_feat[((size_t)((g << 6) + k)) * DD + t] = sum;
}

// Fallback finalize (adj combined via atomics in edge_atomic_kernel).
__global__ __launch_bounds__(1024) void finalize_only_kernel(
    const float* __restrict__ c, const float* __restrict__ sqP,
    const float* __restrict__ crP, const float* __restrict__ entp,
    float* __restrict__ out)
{
  __shared__ float ered[16];
  const int t = threadIdx.x;
  float ent = entp[t];
  #pragma unroll
  for (int off = 32; off; off >>= 1) ent += __shfl_down(ent, off, 64);
  if ((t & 63) == 0) ered[t >> 6] = ent;
  float link = 0.f;
  if (t < 64) {
    const float* cg = c + t * 64;
    float ssq = 0.f;
    #pragma unroll
    for (int k = 0; k < 64; ++k) ssq += cg[k] * cg[k];
    float sq = sqP[t * 4] + sqP[t * 4 + 1] + sqP[t * 4 + 2] + sqP[t * 4 + 3];
    float cr = crP[t * 4] + crP[t * 4 + 1] + crP[t * 4 + 2] + crP[t * 4 + 3];
    float val = sq - 2.0f * cr + ssq;
    link = sqrtf(fmaxf(val, 0.f)) / 16384.0f;
    #pragma unroll
    for (int off = 32; off; off >>= 1) link += __shfl_down(link, off, 64);
  }
  __syncthreads();
  if (t == 0) {
    float es = 0.f;
    #pragma unroll
    for (int i = 0; i < 16; ++i) es += ered[i];
    out[LINK_OFF] = link / 64.0f;
    out[ENT_OFF]  = es / (float)NN;
  }
  for (int r = t; r < 4096; r += 1024) out[BATCH_OFF + r] = (float)(r >> 6);
  if (t < 65) out[BPTR_OFF + t] = (float)(t << 6);
}

extern "C" void kernel_launch(void* const* d_in, const int* in_sizes, int n_in,
                              void* d_out, int out_size, void* d_ws, size_t ws_size,
                              hipStream_t stream) {
  const float* x    = (const float*)d_in[0];
  const float* ew   = (const float*)d_in[1];
  const float* Wm   = (const float*)d_in[2];
  const float* bvec = (const float*)d_in[3];
  const float* gum  = (const float*)d_in[4];
  const int*   eidx = (const int*)d_in[5];
  float* out = (float*)d_out;
  char*  ws  = (char*)d_ws;

  int2*  s1a     = (int2*)(ws + WS_S1A);
  float* c       = (float*)(ws + WS_C);
  float* sqP     = (float*)(ws + WS_SQP);
  float* crP     = (float*)(ws + WS_CRP);
  float* entp    = (float*)(ws + WS_ENTP);
  int2*  sortedp = (int2*)(ws + WS_SORTP);
  int*   goff    = (int*)(ws + WS_GOFF);
  float* adjp    = (float*)(ws + WS_ADJP);

  const int E = in_sizes[1];   // 1048576

  pool_assign_kernel<<<1024, 256, 0, stream>>>(x, Wm, bvec, gum, s1a, entp);
  sort_kernel<<<64, 256, 0, stream>>>(s1a, sortedp, goff, c);
  if (ws_size >= (size_t)WS_NEED) {
    fuse_ge_kernel<<<4352, 256, 0, stream>>>(x, sortedp, goff, eidx, eidx + E,
                                             ew, s1a, out + OUT_OFF, adjp, sqP, crP);
    combine_fin_kernel<<<257, 1024, 0, stream>>>(adjp, c, sqP, crP, entp, out);
  } else {
    hipMemsetAsync(out + ADJ_OFF, 0, (size_t)64 * 4096 * 4, stream);
    sort_kernel<<<64, 256, 0, stream>>>(s1a, sortedp, goff, c);
    gather_kernel<<<4096, 256, 0, stream>>>(x, sortedp, goff, out + OUT_OFF);
    edge_atomic_kernel<<<256, 256, 0, stream>>>(eidx, eidx + E, ew, s1a,
                                                out + ADJ_OFF, sqP, crP);
    finalize_only_kernel<<<1, 1024, 0, stream>>>(c, sqP, crP, entp, out);
  }
}